// Round 1
// baseline (598.770 us; speedup 1.0000x reference)
//
#include <hip/hip_runtime.h>

#define BB 32
#define TT 4096
#define DD 512
#define HH 8
#define HDD 64
#define SCALE_F 0.125f   // 64^-0.5 exact
#define CHUNKS 16
#define TC (TT / CHUNKS) // 256

// ---------------- A1: q[b,i] = enc[b,T-1,:] . Wq[i,:] ----------------
__global__ __launch_bounds__(256) void k_qproj(const float* __restrict__ enc,
                                               const float* __restrict__ Wq,
                                               float* __restrict__ q) {
    __shared__ float x[DD];
    int b = blockIdx.x;
    const float* encLast = enc + ((size_t)b * TT + (TT - 1)) * DD;
    for (int i = threadIdx.x; i < DD; i += 256) x[i] = encLast[i];
    __syncthreads();
    for (int i = threadIdx.x; i < DD; i += 256) {
        const float* wr = Wq + (size_t)i * DD;
        float acc = 0.f;
        for (int d = 0; d < DD; ++d) acc += x[d] * wr[d];
        q[b * DD + i] = acc;
    }
}

// ---------------- A2: u[b,h,d] = SCALE * sum_j q[b,h*64+j] * Wk[h*64+j, d] ----
__global__ __launch_bounds__(256) void k_uvec(const float* __restrict__ q,
                                              const float* __restrict__ Wk,
                                              float* __restrict__ u) {
    int bh = blockIdx.x;
    int b = bh / HH, h = bh % HH;
    __shared__ float qh[HDD];
    if (threadIdx.x < HDD) qh[threadIdx.x] = q[b * DD + h * HDD + threadIdx.x];
    __syncthreads();
    for (int d = threadIdx.x; d < DD; d += 256) {
        float acc = 0.f;
        for (int j = 0; j < HDD; ++j)
            acc += qh[j] * Wk[(size_t)(h * HDD + j) * DD + d];
        u[(size_t)(b * HH + h) * DD + d] = acc * SCALE_F;
    }
}

// ---------------- B: scores[b,t,h] = u[b,h,:] . enc[b,t,:] ----------------
// grid = B*64 blocks (64 row-chunks of 64), 4 waves/block, 1 wave per row.
__global__ __launch_bounds__(256) void k_scores(const float* __restrict__ enc,
                                                const float* __restrict__ u,
                                                float* __restrict__ scores) {
    int blk = blockIdx.x;
    int b = blk >> 6;
    int t0 = (blk & 63) * 64;
    int wave = threadIdx.x >> 6;
    int lane = threadIdx.x & 63;
    // loop-invariant u fragments: lane covers d in [4*lane,4*lane+4) U [256+4*lane, ...)
    float4 uA[HH], uB[HH];
    const float* ub = u + (size_t)b * HH * DD;
#pragma unroll
    for (int h = 0; h < HH; ++h) {
        uA[h] = *(const float4*)(ub + h * DD + 4 * lane);
        uB[h] = *(const float4*)(ub + h * DD + 256 + 4 * lane);
    }
    for (int tt = wave; tt < 64; tt += 4) {
        int t = t0 + tt;
        const float* row = enc + ((size_t)b * TT + t) * DD;
        float4 e0 = *(const float4*)(row + 4 * lane);
        float4 e1 = *(const float4*)(row + 256 + 4 * lane);
        float acc[HH];
#pragma unroll
        for (int h = 0; h < HH; ++h) {
            acc[h] = uA[h].x * e0.x + uA[h].y * e0.y + uA[h].z * e0.z + uA[h].w * e0.w
                   + uB[h].x * e1.x + uB[h].y * e1.y + uB[h].z * e1.z + uB[h].w * e1.w;
        }
#pragma unroll
        for (int h = 0; h < HH; ++h) {
            float v = acc[h];
#pragma unroll
            for (int m = 1; m < 64; m <<= 1) v += __shfl_xor(v, m, 64);
            acc[h] = v;
        }
        if (lane == 0) {
            float* sp = scores + ((size_t)b * TT + t) * HH;
            float4 s0 = {acc[0], acc[1], acc[2], acc[3]};
            float4 s1 = {acc[4], acc[5], acc[6], acc[7]};
            *(float4*)sp = s0;
            *(float4*)(sp + 4) = s1;
        }
    }
}

// ---------------- C: softmax over t for each (b,h); scores/weights are [B,T,H] ----
__global__ __launch_bounds__(256) void k_softmax(const float* __restrict__ scores,
                                                 float* __restrict__ weights) {
    int b = blockIdx.x / HH, h = blockIdx.x % HH;
    const float* sp = scores + (size_t)b * TT * HH + h;
    float* wp = weights + (size_t)b * TT * HH + h;
    int tid = threadIdx.x;
    int wave = tid >> 6, lane = tid & 63;
    __shared__ float red[8];
    float vals[TT / 256];
#pragma unroll
    for (int k = 0; k < TT / 256; ++k) vals[k] = sp[(size_t)(tid + 256 * k) * HH];
    float m = -1e30f;
#pragma unroll
    for (int k = 0; k < TT / 256; ++k) m = fmaxf(m, vals[k]);
#pragma unroll
    for (int msk = 1; msk < 64; msk <<= 1) m = fmaxf(m, __shfl_xor(m, msk, 64));
    if (lane == 0) red[wave] = m;
    __syncthreads();
    m = fmaxf(fmaxf(red[0], red[1]), fmaxf(red[2], red[3]));
    float s = 0.f;
#pragma unroll
    for (int k = 0; k < TT / 256; ++k) { vals[k] = __expf(vals[k] - m); s += vals[k]; }
#pragma unroll
    for (int msk = 1; msk < 64; msk <<= 1) s += __shfl_xor(s, msk, 64);
    __syncthreads();
    if (lane == 0) red[4 + wave] = s;
    __syncthreads();
    s = red[4] + red[5] + red[6] + red[7];
    float inv = 1.0f / s;
#pragma unroll
    for (int k = 0; k < TT / 256; ++k) wp[(size_t)(tid + 256 * k) * HH] = vals[k] * inv;
}

// ---------------- D: out1[b,t] = mean_h weights[b,t,h] ----------------
__global__ __launch_bounds__(256) void k_wmean(const float* __restrict__ weights,
                                               float* __restrict__ out1) {
    size_t i = (size_t)blockIdx.x * 256 + threadIdx.x; // over B*T
    const float4* wp = (const float4*)(weights + i * HH);
    float4 a = wp[0], c = wp[1];
    out1[i] = (a.x + a.y + a.z + a.w + c.x + c.y + c.z + c.w) * 0.125f;
}

// ---------------- E: partial[b,c,h,d] = sum_{t in chunk c} w[b,t,h]*enc[b,t,d] ----
__global__ __launch_bounds__(256) void k_wsum(const float* __restrict__ enc,
                                              const float* __restrict__ weights,
                                              float* __restrict__ partial) {
    int b = blockIdx.x / CHUNKS, c = blockIdx.x % CHUNKS;
    int t0 = c * TC;
    int tid = threadIdx.x;
    float2 acc[HH];
#pragma unroll
    for (int h = 0; h < HH; ++h) { acc[h].x = 0.f; acc[h].y = 0.f; }
    __shared__ float wl[64 * HH]; // weights for 64 rows
    for (int ts = 0; ts < TC; ts += 64) {
        __syncthreads();
        { // stage 64 rows x 8 heads of weights (coalesced float2/thread)
            float2 tmp = *(const float2*)(weights + ((size_t)b * TT + t0 + ts) * HH + tid * 2);
            *(float2*)(wl + tid * 2) = tmp;
        }
        __syncthreads();
#pragma unroll 4
        for (int r = 0; r < 64; ++r) {
            int t = t0 + ts + r;
            float2 e = *(const float2*)(enc + ((size_t)b * TT + t) * DD + tid * 2);
            float4 w0 = *(const float4*)(wl + r * HH);     // broadcast reads
            float4 w1 = *(const float4*)(wl + r * HH + 4);
            acc[0].x += w0.x * e.x; acc[0].y += w0.x * e.y;
            acc[1].x += w0.y * e.x; acc[1].y += w0.y * e.y;
            acc[2].x += w0.z * e.x; acc[2].y += w0.z * e.y;
            acc[3].x += w0.w * e.x; acc[3].y += w0.w * e.y;
            acc[4].x += w1.x * e.x; acc[4].y += w1.x * e.y;
            acc[5].x += w1.y * e.x; acc[5].y += w1.y * e.y;
            acc[6].x += w1.z * e.x; acc[6].y += w1.z * e.y;
            acc[7].x += w1.w * e.x; acc[7].y += w1.w * e.y;
        }
    }
    float* pp = partial + ((size_t)(b * CHUNKS + c) * HH) * DD;
#pragma unroll
    for (int h = 0; h < HH; ++h)
        *(float2*)(pp + h * DD + tid * 2) = acc[h];
}

// ---------------- F: ctx[b,h,d] = sum_c partial[b,c,h,d] ----------------
__global__ __launch_bounds__(256) void k_pred(const float* __restrict__ partial,
                                              float* __restrict__ ctx) {
    size_t i = (size_t)blockIdx.x * 256 + threadIdx.x; // over B*H*D
    size_t b = i / (HH * DD);
    size_t r = i % (HH * DD);
    float acc = 0.f;
    for (int c = 0; c < CHUNKS; ++c)
        acc += partial[(b * CHUNKS + c) * (HH * DD) + r];
    ctx[i] = acc;
}

// ---------------- G1: ctxv[b,i] = sum_d Wv[i,d] * ctx[b, i/64, d] ----------------
__global__ __launch_bounds__(256) void k_vproj(const float* __restrict__ Wv,
                                               const float* __restrict__ ctx,
                                               float* __restrict__ ctxv) {
    int b = blockIdx.x;
    __shared__ float cx[HH * DD];
    for (int i = threadIdx.x; i < HH * DD; i += 256) cx[i] = ctx[(size_t)b * HH * DD + i];
    __syncthreads();
    for (int i = threadIdx.x; i < DD; i += 256) {
        int h = i / HDD;
        const float* wr = Wv + (size_t)i * DD;
        const float* cc = cx + h * DD;
        float acc = 0.f;
        for (int d = 0; d < DD; ++d) acc += wr[d] * cc[d];
        ctxv[b * DD + i] = acc;
    }
}

// ---------------- G2: out0[b,o] = sum_i Wo[o,i] * ctxv[b,i] ----------------
__global__ __launch_bounds__(256) void k_oproj(const float* __restrict__ Wo,
                                               const float* __restrict__ ctxv,
                                               float* __restrict__ out0) {
    int b = blockIdx.x;
    __shared__ float cv[DD];
    for (int i = threadIdx.x; i < DD; i += 256) cv[i] = ctxv[(size_t)b * DD + i];
    __syncthreads();
    for (int o = threadIdx.x; o < DD; o += 256) {
        const float* wr = Wo + (size_t)o * DD;
        float acc = 0.f;
        for (int d = 0; d < DD; ++d) acc += wr[d] * cv[d];
        out0[b * DD + o] = acc;
    }
}

extern "C" void kernel_launch(void* const* d_in, const int* in_sizes, int n_in,
                              void* d_out, int out_size, void* d_ws, size_t ws_size,
                              hipStream_t stream) {
    const float* enc = (const float*)d_in[0];
    const float* Wq  = (const float*)d_in[1];
    const float* Wk  = (const float*)d_in[2];
    const float* Wv  = (const float*)d_in[3];
    const float* Wo  = (const float*)d_in[4];

    float* ws = (float*)d_ws;
    float* q       = ws;                        // B*D          = 16384
    float* u       = q + BB * DD;               // B*H*D        = 131072
    float* scores  = u + BB * HH * DD;          // B*T*H        = 1048576
    float* weights = scores + (size_t)BB * TT * HH;  // B*T*H   = 1048576
    float* partial = weights + (size_t)BB * TT * HH; // B*CH*H*D= 2097152
    float* ctx     = partial + (size_t)BB * CHUNKS * HH * DD; // 131072
    float* ctxv    = ctx + BB * HH * DD;        // 16384
    // total ~4.49M floats (~17.1 MB) of ws

    float* out0 = (float*)d_out;             // [B, D]
    float* out1 = out0 + BB * DD;            // [B, T]

    hipLaunchKernelGGL(k_qproj,   dim3(BB),            dim3(256), 0, stream, enc, Wq, q);
    hipLaunchKernelGGL(k_uvec,    dim3(BB * HH),       dim3(256), 0, stream, q, Wk, u);
    hipLaunchKernelGGL(k_scores,  dim3(BB * 64),       dim3(256), 0, stream, enc, u, scores);
    hipLaunchKernelGGL(k_softmax, dim3(BB * HH),       dim3(256), 0, stream, scores, weights);
    hipLaunchKernelGGL(k_wmean,   dim3(BB * TT / 256), dim3(256), 0, stream, weights, out1);
    hipLaunchKernelGGL(k_wsum,    dim3(BB * CHUNKS),   dim3(256), 0, stream, enc, weights, partial);
    hipLaunchKernelGGL(k_pred,    dim3(BB * HH * DD / 256), dim3(256), 0, stream, partial, ctx);
    hipLaunchKernelGGL(k_vproj,   dim3(BB),            dim3(256), 0, stream, Wv, ctx, ctxv);
    hipLaunchKernelGGL(k_oproj,   dim3(BB),            dim3(256), 0, stream, Wo, ctxv, out0);
}